// Round 1
// baseline (2165.734 us; speedup 1.0000x reference)
//
#include <hip/hip_runtime.h>
#include <hip/hip_bf16.h>
#include <math.h>

constexpr int NN = 100000;
constexpr int EE = 1000000;
constexpr int RRR = 3;
constexpr int DIN = 128;
constexpr int DOUT = 64;
constexpr float SLOPE = 0.2f;

// sortable-uint encoding for float atomicMax (handles negatives)
__device__ __forceinline__ unsigned enc_f(float f) {
    unsigned b = __float_as_uint(f);
    return (b & 0x80000000u) ? ~b : (b | 0x80000000u);
}
__device__ __forceinline__ float dec_f(unsigned u) {
    return (u & 0x80000000u) ? __uint_as_float(u & 0x7fffffffu) : __uint_as_float(~u);
}

// h[r] = x @ W[r]; als[r][n] = h[r][n]·a_src[r]; ald[r][n] = h[r][n]·a_dst[r]
// block: 256 thr (4 waves), handles 32 rows for one relation (blockIdx.y)
template<int INP>
__global__ __launch_bounds__(256) void gemm_att(
    const float* __restrict__ x,     // [NN, INP]
    const float* __restrict__ W,     // [R, INP, 64]
    const float* __restrict__ asrc,  // [R, 64]
    const float* __restrict__ adst,  // [R, 64]
    float* __restrict__ h,           // [R, NN, 64]
    float* __restrict__ als,         // [R, NN]
    float* __restrict__ ald)         // [R, NN]
{
    constexpr int WS = INP + 4;           // pad: stride 132 floats -> 16B-aligned, 8 words/bank (optimal)
    __shared__ float Wt[64 * WS];         // W transposed: Wt[col][k]
    __shared__ float xs[32 * INP];        // 32 x-rows
    const int r = blockIdx.y;
    const int row0 = blockIdx.x * 32;     // NN/32 = 3125 exact
    const int t = threadIdx.x;
    const int lane = t & 63;
    const int warp = t >> 6;

    const float* Wr = W + r * (INP * DOUT);
    for (int idx = t; idx < INP * DOUT; idx += 256) {
        int k = idx >> 6, c = idx & 63;
        Wt[c * WS + k] = Wr[idx];
    }
    const float4* xg = (const float4*)(x + (size_t)row0 * INP);
    float4* xs4 = (float4*)xs;
    for (int i = t; i < 32 * INP / 4; i += 256) xs4[i] = xg[i];
    float av = asrc[r * DOUT + lane];
    float dv = adst[r * DOUT + lane];
    __syncthreads();

    float acc[8];
#pragma unroll
    for (int i = 0; i < 8; ++i) acc[i] = 0.f;
    const int rbase = warp * 8;
#pragma unroll 2
    for (int k4 = 0; k4 < INP / 4; ++k4) {
        float4 wv = *(const float4*)(&Wt[lane * WS + k4 * 4]);   // conflict-free b128
#pragma unroll
        for (int rr = 0; rr < 8; ++rr) {
            float4 xv = *(const float4*)(&xs[(rbase + rr) * INP + k4 * 4]);  // wave-uniform broadcast
            acc[rr] = fmaf(xv.x, wv.x, acc[rr]);
            acc[rr] = fmaf(xv.y, wv.y, acc[rr]);
            acc[rr] = fmaf(xv.z, wv.z, acc[rr]);
            acc[rr] = fmaf(xv.w, wv.w, acc[rr]);
        }
    }
#pragma unroll
    for (int rr = 0; rr < 8; ++rr) {
        int node = row0 + rbase + rr;
        h[((size_t)r * NN + node) * DOUT + lane] = acc[rr];
        float s1 = acc[rr] * av, s2 = acc[rr] * dv;
#pragma unroll
        for (int off = 32; off; off >>= 1) {
            s1 += __shfl_xor(s1, off);
            s2 += __shfl_xor(s2, off);
        }
        if (lane == 0) { als[r * NN + node] = s1; ald[r * NN + node] = s2; }
    }
}

// pass 1: e = leaky_relu(als[src]+ald[dst]); segment-max via encoded atomicMax
__global__ __launch_bounds__(256) void edge_logits_max(
    const int* __restrict__ ei0, const int* __restrict__ ei1, const int* __restrict__ ei2,
    const float* __restrict__ als, const float* __restrict__ ald,
    float* __restrict__ ebuf, unsigned* __restrict__ mbuf)
{
    int e = blockIdx.x * 256 + threadIdx.x;
    if (e >= EE) return;
    int r = blockIdx.y;
    const int* ei = (r == 0) ? ei0 : ((r == 1) ? ei1 : ei2);
    int src = ei[e], dst = ei[EE + e];
    float s = als[r * NN + src] + ald[r * NN + dst];
    float lr = (s > 0.f) ? s : SLOPE * s;
    ebuf[r * EE + e] = lr;
    atomicMax(&mbuf[r * NN + dst], enc_f(lr));
}

// pass 2: num = exp(e - m[dst]); den[dst] += num
__global__ __launch_bounds__(256) void edge_exp_den(
    const int* __restrict__ ei0, const int* __restrict__ ei1, const int* __restrict__ ei2,
    const unsigned* __restrict__ mbuf, float* __restrict__ ebuf, float* __restrict__ den)
{
    int e = blockIdx.x * 256 + threadIdx.x;
    if (e >= EE) return;
    int r = blockIdx.y;
    const int* ei = (r == 0) ? ei0 : ((r == 1) ? ei1 : ei2);
    int dst = ei[EE + e];
    float lr = ebuf[r * EE + e];
    float mv = dec_f(mbuf[r * NN + dst]);
    float num = expf(lr - mv);
    ebuf[r * EE + e] = num;
    atomicAdd(&den[r * NN + dst], num);
}

// pass 3: acc[dst] += (num/den[dst]) * h[src]   (wave per edge, lane = feature)
__global__ __launch_bounds__(256) void edge_scatter(
    const int* __restrict__ ei0, const int* __restrict__ ei1, const int* __restrict__ ei2,
    const float* __restrict__ h, const float* __restrict__ ebuf,
    const float* __restrict__ den, float* __restrict__ acc)
{
    int e = blockIdx.x * 4 + (threadIdx.x >> 6);   // EE/4 = 250000 exact
    if (e >= EE) return;
    int lane = threadIdx.x & 63;
    int r = blockIdx.y;
    const int* ei = (r == 0) ? ei0 : ((r == 1) ? ei1 : ei2);
    int src = ei[e], dst = ei[EE + e];
    float coef = ebuf[r * EE + e] / den[r * NN + dst];
    float v = coef * h[((size_t)r * NN + src) * DOUT + lane];
    atomicAdd(&acc[(size_t)dst * DOUT + lane], v);
}

// between layers: hmid = relu(l2norm((acc + sum_r b1[r]) / 3))
__global__ __launch_bounds__(256) void midnorm(
    const float* __restrict__ acc, const float* __restrict__ b1, float* __restrict__ hmid)
{
    int node = blockIdx.x * 4 + (threadIdx.x >> 6);
    if (node >= NN) return;
    int lane = threadIdx.x & 63;
    float bsum = b1[lane] + b1[64 + lane] + b1[128 + lane];
    float v = (acc[(size_t)node * DOUT + lane] + bsum) * (1.0f / 3.0f);
    float ss = v * v;
#pragma unroll
    for (int off = 32; off; off >>= 1) ss += __shfl_xor(ss, off);
    float nrm = sqrtf(ss);
    float d = fmaxf(nrm, 1e-12f);
    hmid[(size_t)node * DOUT + lane] = fmaxf(v / d, 0.0f);
}

// finalize: out = (acc + sum_r b2[r]) / 3
__global__ __launch_bounds__(256) void final_bias(float* __restrict__ out, const float* __restrict__ b2)
{
    int idx = blockIdx.x * 256 + threadIdx.x;
    if (idx >= NN * DOUT) return;
    int c = idx & 63;
    float bsum = b2[c] + b2[64 + c] + b2[128 + c];
    out[idx] = (out[idx] + bsum) * (1.0f / 3.0f);
}

extern "C" void kernel_launch(void* const* d_in, const int* in_sizes, int n_in,
                              void* d_out, int out_size, void* d_ws, size_t ws_size,
                              hipStream_t stream) {
    const float* x   = (const float*)d_in[0];
    const int* ei0   = (const int*)d_in[1];
    const int* ei1   = (const int*)d_in[2];
    const int* ei2   = (const int*)d_in[3];
    const float* W1  = (const float*)d_in[4];
    const float* as1 = (const float*)d_in[5];
    const float* ad1 = (const float*)d_in[6];
    const float* b1  = (const float*)d_in[7];
    const float* W2  = (const float*)d_in[8];
    const float* as2 = (const float*)d_in[9];
    const float* ad2 = (const float*)d_in[10];
    const float* b2  = (const float*)d_in[11];
    float* out = (float*)d_out;

    // workspace carve-up (floats): total ~119.2 MB
    float* ws = (float*)d_ws;
    size_t off = 0;
    float* h    = ws + off; off += (size_t)RRR * NN * DOUT;   // 19.2M
    float* als  = ws + off; off += (size_t)RRR * NN;
    float* ald  = ws + off; off += (size_t)RRR * NN;
    unsigned* mbuf = (unsigned*)(ws + off); off += (size_t)RRR * NN;  // + den below: one memset
    float* den  = ws + off; off += (size_t)RRR * NN;
    float* ebuf = ws + off; off += (size_t)RRR * EE;          // 3M
    float* hmid = ws + off; off += (size_t)NN * DOUT;         // 6.4M

    dim3 blk(256);
    dim3 gG(NN / 32, RRR);            // 3125 x 3
    dim3 gE((EE + 255) / 256, RRR);   // 3907 x 3
    dim3 gS(EE / 4, RRR);             // 250000 x 3
    int gM = (NN + 3) / 4;            // 25000
    int gF = (NN * DOUT + 255) / 256; // 25000

    // ---- layer 1 ----
    hipMemsetAsync(mbuf, 0, (size_t)RRR * NN * 2 * sizeof(float), stream); // mbuf+den
    hipMemsetAsync(out, 0, (size_t)NN * DOUT * sizeof(float), stream);
    gemm_att<DIN><<<gG, blk, 0, stream>>>(x, W1, as1, ad1, h, als, ald);
    edge_logits_max<<<gE, blk, 0, stream>>>(ei0, ei1, ei2, als, ald, ebuf, mbuf);
    edge_exp_den<<<gE, blk, 0, stream>>>(ei0, ei1, ei2, mbuf, ebuf, den);
    edge_scatter<<<gS, blk, 0, stream>>>(ei0, ei1, ei2, h, ebuf, den, out);
    midnorm<<<gM, blk, 0, stream>>>(out, b1, hmid);

    // ---- layer 2 ----
    hipMemsetAsync(mbuf, 0, (size_t)RRR * NN * 2 * sizeof(float), stream);
    hipMemsetAsync(out, 0, (size_t)NN * DOUT * sizeof(float), stream);
    gemm_att<DOUT><<<gG, blk, 0, stream>>>(hmid, W2, as2, ad2, h, als, ald);
    edge_logits_max<<<gE, blk, 0, stream>>>(ei0, ei1, ei2, als, ald, ebuf, mbuf);
    edge_exp_den<<<gE, blk, 0, stream>>>(ei0, ei1, ei2, mbuf, ebuf, den);
    edge_scatter<<<gS, blk, 0, stream>>>(ei0, ei1, ei2, h, ebuf, den, out);
    final_bias<<<gF, blk, 0, stream>>>(out, b2);
}

// Round 2
// 1040.269 us; speedup vs baseline: 2.0819x; 2.0819x over previous
//
#include <hip/hip_runtime.h>
#include <hip/hip_bf16.h>
#include <math.h>

constexpr int NN = 100000;
constexpr int EE = 1000000;
constexpr int RRR = 3;
constexpr int DIN = 128;
constexpr int DOUT = 64;
constexpr float SLOPE = 0.2f;
constexpr int NR = RRR * NN;                      // 300000 segments (concatenated by relation)
constexpr int SCAN_CHUNK = 1024;
constexpr int NBLK = (NR + SCAN_CHUNK - 1) / SCAN_CHUNK;   // 293

// ---------------- GEMM + attention logits (unchanged from R1, it was not hot) ----------------
// h[r] = x @ W[r]; als[r][n] = h[r][n]·a_src[r]; ald[r][n] = h[r][n]·a_dst[r]
template<int INP>
__global__ __launch_bounds__(256) void gemm_att(
    const float* __restrict__ x,     // [NN, INP]
    const float* __restrict__ W,     // [R, INP, 64]
    const float* __restrict__ asrc,  // [R, 64]
    const float* __restrict__ adst,  // [R, 64]
    float* __restrict__ h,           // [R, NN, 64]
    float* __restrict__ als,         // [R, NN]
    float* __restrict__ ald)         // [R, NN]
{
    constexpr int WS = INP + 4;           // stride 132/68 floats: conflict-free b128
    __shared__ float Wt[64 * WS];         // W transposed: Wt[col][k]
    __shared__ float xs[32 * INP];        // 32 x-rows
    const int r = blockIdx.y;
    const int row0 = blockIdx.x * 32;     // NN/32 = 3125 exact
    const int t = threadIdx.x;
    const int lane = t & 63;
    const int warp = t >> 6;

    const float* Wr = W + r * (INP * DOUT);
    for (int idx = t; idx < INP * DOUT; idx += 256) {
        int k = idx >> 6, c = idx & 63;
        Wt[c * WS + k] = Wr[idx];
    }
    const float4* xg = (const float4*)(x + (size_t)row0 * INP);
    float4* xs4 = (float4*)xs;
    for (int i = t; i < 32 * INP / 4; i += 256) xs4[i] = xg[i];
    float av = asrc[r * DOUT + lane];
    float dv = adst[r * DOUT + lane];
    __syncthreads();

    float acc[8];
#pragma unroll
    for (int i = 0; i < 8; ++i) acc[i] = 0.f;
    const int rbase = warp * 8;
#pragma unroll 2
    for (int k4 = 0; k4 < INP / 4; ++k4) {
        float4 wv = *(const float4*)(&Wt[lane * WS + k4 * 4]);
#pragma unroll
        for (int rr = 0; rr < 8; ++rr) {
            float4 xv = *(const float4*)(&xs[(rbase + rr) * INP + k4 * 4]);  // wave-uniform broadcast
            acc[rr] = fmaf(xv.x, wv.x, acc[rr]);
            acc[rr] = fmaf(xv.y, wv.y, acc[rr]);
            acc[rr] = fmaf(xv.z, wv.z, acc[rr]);
            acc[rr] = fmaf(xv.w, wv.w, acc[rr]);
        }
    }
#pragma unroll
    for (int rr = 0; rr < 8; ++rr) {
        int node = row0 + rbase + rr;
        h[((size_t)r * NN + node) * DOUT + lane] = acc[rr];
        float s1 = acc[rr] * av, s2 = acc[rr] * dv;
#pragma unroll
        for (int off = 32; off; off >>= 1) {
            s1 += __shfl_xor(s1, off);
            s2 += __shfl_xor(s2, off);
        }
        if (lane == 0) { als[r * NN + node] = s1; ald[r * NN + node] = s2; }
    }
}

// ---------------- CSR build (once per call, shared by both layers) ----------------

__global__ __launch_bounds__(256) void deg_hist(
    const int* __restrict__ ei0, const int* __restrict__ ei1, const int* __restrict__ ei2,
    unsigned* __restrict__ deg)
{
    int e = blockIdx.x * 256 + threadIdx.x;
    if (e >= EE) return;
    int r = blockIdx.y;
    const int* ei = (r == 0) ? ei0 : ((r == 1) ? ei1 : ei2);
    atomicAdd(&deg[r * NN + ei[EE + e]], 1u);
}

// per-chunk (1024 elems) exclusive scan; chunk totals -> bsum
__global__ __launch_bounds__(256) void scan_block(
    const unsigned* __restrict__ deg, unsigned* __restrict__ off, unsigned* __restrict__ bsum)
{
    __shared__ unsigned tsum[256];
    const int base = blockIdx.x * SCAN_CHUNK;
    const int t = threadIdx.x;
    const int i0 = base + t * 4;
    unsigned v[4];
#pragma unroll
    for (int k = 0; k < 4; ++k) v[k] = (i0 + k < NR) ? deg[i0 + k] : 0u;
    unsigned run = 0;
#pragma unroll
    for (int k = 0; k < 4; ++k) { unsigned x = v[k]; v[k] = run; run += x; }  // thread-local exclusive
    tsum[t] = run;
    __syncthreads();
    unsigned val = run;                       // Hillis-Steele inclusive scan of thread totals
    for (int d = 1; d < 256; d <<= 1) {
        unsigned add = (t >= d) ? tsum[t - d] : 0u;
        __syncthreads();
        val += add;
        tsum[t] = val;
        __syncthreads();
    }
    unsigned texcl = val - run;               // exclusive prefix of this thread within chunk
    if (t == 255) bsum[blockIdx.x] = val;     // chunk total
#pragma unroll
    for (int k = 0; k < 4; ++k)
        if (i0 + k < NR) off[i0 + k] = texcl + v[k];
}

__global__ __launch_bounds__(256) void scan_bsums(unsigned* __restrict__ bsum)
{
    __shared__ unsigned s[NBLK];
    int t = threadIdx.x;
    for (int i = t; i < NBLK; i += 256) s[i] = bsum[i];
    __syncthreads();
    if (t == 0) {
        unsigned run = 0;
        for (int i = 0; i < NBLK; ++i) { unsigned x = s[i]; s[i] = run; run += x; }
    }
    __syncthreads();
    for (int i = t; i < NBLK; i += 256) bsum[i] = s[i];
}

// finalize offsets; also initialize the fill cursor (reuses the deg array)
__global__ __launch_bounds__(256) void add_off(
    unsigned* __restrict__ off, const unsigned* __restrict__ bsum, unsigned* __restrict__ cursor)
{
    int i = blockIdx.x * 256 + threadIdx.x;
    if (i >= NR) return;
    unsigned o = off[i] + bsum[i / SCAN_CHUNK];
    off[i] = o;
    cursor[i] = o;
}

__global__ __launch_bounds__(256) void csr_fill(
    const int* __restrict__ ei0, const int* __restrict__ ei1, const int* __restrict__ ei2,
    unsigned* __restrict__ cursor, int* __restrict__ csr_src)
{
    int e = blockIdx.x * 256 + threadIdx.x;
    if (e >= EE) return;
    int r = blockIdx.y;
    const int* ei = (r == 0) ? ei0 : ((r == 1) ? ei1 : ei2);
    int src = ei[e], dst = ei[EE + e];
    unsigned pos = atomicAdd(&cursor[r * NN + dst], 1u);
    csr_src[pos] = src;
}

// ---------------- fused per-layer aggregation: online segment-softmax + weighted gather ----------------
// one wave per dst node; 3 relations serial; lane = feature. Writes each output once (no atomics).
// L1: epilogue = relu(l2norm((sum_r + sum_r b)/3)); L2: epilogue = (sum_r + sum_r b)/3.
template<bool L1>
__global__ __launch_bounds__(256) void aggregate(
    const int* __restrict__ csr_src, const unsigned* __restrict__ off,
    const float* __restrict__ h,     // [R, NN, 64]
    const float* __restrict__ als, const float* __restrict__ ald,  // [R, NN]
    const float* __restrict__ bias,  // [R, 64]
    float* __restrict__ outp)        // [NN, 64]
{
    int node = blockIdx.x * 4 + (threadIdx.x >> 6);
    if (node >= NN) return;
    int lane = threadIdx.x & 63;
    float total = 0.f;
#pragma unroll
    for (int r = 0; r < RRR; ++r) {
        int idx = r * NN + node;
        unsigned start = off[idx];
        unsigned end = (idx == NR - 1) ? (unsigned)((size_t)RRR * EE) : off[idx + 1];
        int cnt = (int)(end - start);
        if (cnt <= 0) continue;
        float aldv = ald[idx];
        const float* hr = h + (size_t)r * NN * DOUT;
        const float* alsr = als + (size_t)r * NN;
        float m = -3.4e38f, den = 0.f, acc = 0.f;
        int src_nxt = csr_src[start];
        for (int j = 0; j < cnt; ++j) {
            int src = src_nxt;
            if (j + 1 < cnt) src_nxt = csr_src[start + j + 1];   // prefetch next index
            float hv = hr[(size_t)src * DOUT + lane];            // coalesced 256B, LLC-resident
            float sv = alsr[src] + aldv;                          // wave-uniform
            float lr = (sv > 0.f) ? sv : SLOPE * sv;
            if (lr > m) {                                         // wave-uniform branch
                float sc = __expf(m - lr);                        // 0 on first edge
                den *= sc; acc *= sc; m = lr;
            }
            float p = __expf(lr - m);
            den += p;
            acc = fmaf(p, hv, acc);
        }
        total += acc / den;
    }
    float bsum = bias[lane] + bias[64 + lane] + bias[128 + lane];
    float v = (total + bsum) * (1.0f / 3.0f);
    if (L1) {
        float ss = v * v;
#pragma unroll
        for (int o = 32; o; o >>= 1) ss += __shfl_xor(ss, o);
        float d = fmaxf(sqrtf(ss), 1e-12f);
        v = fmaxf(v / d, 0.f);
    }
    outp[(size_t)node * DOUT + lane] = v;
}

// ---------------- launch ----------------
extern "C" void kernel_launch(void* const* d_in, const int* in_sizes, int n_in,
                              void* d_out, int out_size, void* d_ws, size_t ws_size,
                              hipStream_t stream) {
    const float* x   = (const float*)d_in[0];
    const int* ei0   = (const int*)d_in[1];
    const int* ei1   = (const int*)d_in[2];
    const int* ei2   = (const int*)d_in[3];
    const float* W1  = (const float*)d_in[4];
    const float* as1 = (const float*)d_in[5];
    const float* ad1 = (const float*)d_in[6];
    const float* b1  = (const float*)d_in[7];
    const float* W2  = (const float*)d_in[8];
    const float* as2 = (const float*)d_in[9];
    const float* ad2 = (const float*)d_in[10];
    const float* b2  = (const float*)d_in[11];
    float* out = (float*)d_out;

    // workspace carve-up (4B units): total ~119.2 MB
    float* ws = (float*)d_ws;
    size_t off_u = 0;
    float* h      = ws + off_u; off_u += (size_t)RRR * NN * DOUT;  // 19.2M
    float* als    = ws + off_u; off_u += (size_t)RRR * NN;
    float* ald    = ws + off_u; off_u += (size_t)RRR * NN;
    unsigned* deg = (unsigned*)(ws + off_u); off_u += NR;          // reused as fill cursor
    unsigned* off = (unsigned*)(ws + off_u); off_u += NR;
    unsigned* bsum= (unsigned*)(ws + off_u); off_u += 512;
    int* csr_src  = (int*)(ws + off_u); off_u += (size_t)RRR * EE; // 3M
    float* hmid   = ws + off_u; off_u += (size_t)NN * DOUT;        // 6.4M

    dim3 blk(256);
    dim3 gG(NN / 32, RRR);            // 3125 x 3
    dim3 gE((EE + 255) / 256, RRR);   // 3907 x 3
    int gA = NN / 4;                  // 25000
    int gO = (NR + 255) / 256;

    // ---- CSR build (shared by both layers) ----
    hipMemsetAsync(deg, 0, (size_t)NR * sizeof(unsigned), stream);
    deg_hist<<<gE, blk, 0, stream>>>(ei0, ei1, ei2, deg);
    scan_block<<<NBLK, blk, 0, stream>>>(deg, off, bsum);
    scan_bsums<<<1, blk, 0, stream>>>(bsum);
    add_off<<<gO, blk, 0, stream>>>(off, bsum, deg);   // deg becomes cursor
    csr_fill<<<gE, blk, 0, stream>>>(ei0, ei1, ei2, deg, csr_src);

    // ---- layer 1 ----
    gemm_att<DIN><<<gG, blk, 0, stream>>>(x, W1, as1, ad1, h, als, ald);
    aggregate<true><<<gA, blk, 0, stream>>>(csr_src, off, h, als, ald, b1, hmid);

    // ---- layer 2 ----
    gemm_att<DOUT><<<gG, blk, 0, stream>>>(hmid, W2, as2, ad2, h, als, ald);
    aggregate<false><<<gA, blk, 0, stream>>>(csr_src, off, h, als, ald, b2, out);
}